// Round 11
// baseline (12.850 us; speedup 1.0000x reference)
//
#include <hip/hip_runtime.h>

// ---------------------------------------------------------------------------
// 9-state/3-control LQR decouples per axis into a 3-state (p,v,a | jerk)
// chain; axes 0,1 = type 0, axis 2 (yaw) = type 1. Riccati table computed at
// COMPILE TIME (double precision) and folded to literals via full unroll +
// template-constant type. Recursion dependent chain is REGISTER-ONLY (kk[80]
// constant-indexed -> VGPRs).
// This round (vs R8, single variable): backward pass reads targets DIRECTLY
// from global (80 independent 4B loads/lane, issued ahead by the compiler;
// block working set 15KB fits L1) -> staging phase + first barrier deleted.
// LDS is now only the forward pass's out-layout buffer + coalesced writeback
// (the R8/R10-validated store path). BPB=16, NTH=96, grid=512 (2 blk/CU).
// ---------------------------------------------------------------------------
struct Tbl {
    float qx0[81], qx1[81], qx2[81], dm[81];   // Qxu, dm = DT * (-1/Quu)
    float k0[81],  k1[81],  k2[81];            // feedback gains K_t
};

constexpr Tbl make_tbl(int TY) {
    Tbl T{};
    const double dt = 0.1, dt2 = 0.01, dt3 = 0.001;
    const double cxp = TY ? 10.0 : 1.0;        // YAW_W vs 1
    const double cxv = TY ? 1.0  : 0.0;        // YAW_VEL_W vs 0
    double v00=0, v01=0, v02=0, v11=0, v12=0, v22=0;
    for (int t = 80; t >= 0; --t) {
        const double on = (t >= 1) ? 1.0 : 0.0;     // C[0] == 0
        double Vb0 = v00*dt3 + v01*dt2 + v02*dt;
        double Vb1 = v01*dt3 + v11*dt2 + v12*dt;
        double Vb2 = v02*dt3 + v12*dt2 + v22*dt;
        double Quu = on*0.1 + dt3*Vb0 + dt2*Vb1 + dt*Vb2;
        double Qxu0 = Vb0;
        double Qxu1 = dt*Vb0 + Vb1;
        double Qxu2 = dt2*Vb0 + dt*Vb1 + Vb2;
        double M01 = dt*v00 + v01;
        double M02 = dt2*v00 + dt*v01 + v02;
        double M11 = dt*v01 + v11;
        double M12 = dt2*v01 + dt*v11 + v12;
        double M22 = dt2*v02 + dt*v12 + v22;
        double Q00 = on*cxp + v00;
        double Q11 = on*cxv + dt*M01 + M11;
        double Q12 = dt*M02 + M12;
        double Q22 = on*1.0 + dt2*M02 + dt*M12 + M22;
        double m = -1.0 / Quu;
        T.qx0[t] = (float)Qxu0; T.qx1[t] = (float)Qxu1; T.qx2[t] = (float)Qxu2;
        T.dm[t]  = (float)(dt * m);
        T.k0[t]  = (float)(Qxu0*m); T.k1[t] = (float)(Qxu1*m); T.k2[t] = (float)(Qxu2*m);
        v00 = Q00 + m*Qxu0*Qxu0;               // Vn = Qxx + m*Qxu*Qxu^T
        v01 = M01 + m*Qxu0*Qxu1;               // (Qux + Quu*K == 0)
        v02 = M02 + m*Qxu0*Qxu2;
        v11 = Q11 + m*Qxu1*Qxu1;
        v12 = Q12 + m*Qxu1*Qxu2;
        v22 = Q22 + m*Qxu2*Qxu2;
    }
    return T;
}

// Register-resident recursion. Targets read straight from global (gt =
// &ap[b*1440+1200+axis]; 80 independent loads, compiler issues them early;
// 15KB/block working set is L1-resident after first touch). Forward writes
// p_t into the LDS out-layout buffer (row = &sm[bb*RS+axis]).
template <int TY>
__device__ __forceinline__ void do_axis(const float* __restrict__ gt,
                                        float* __restrict__ row,
                                        float p, float ve, float ac) {
    constexpr Tbl T = make_tbl(TY);
    constexpr float wp = TY ? 10.f : 1.f;
    float kk[80];

    // ---- backward: v-recursion in registers; tg loads are off-chain ----
    float v0 = 0.f, v1 = 0.f, v2 = 0.f;
#pragma unroll
    for (int t = 80; t >= 1; --t) {
        float tg = gt[(t - 1) * 3];            // independent address, prefetchable
        float a1 = fmaf(0.1f, v0, v1);
        float a2 = fmaf(0.1f, a1, v2);
        float k  = T.dm[t] * a2;               // k_t = -(b^T v)/Quu
        v0 = fmaf(T.qx0[t], k, v0) - wp * tg;
        v1 = fmaf(T.qx1[t], k, a1);
        v2 = fmaf(T.qx2[t], k, a2);
        if (t <= 79) kk[t] = k;                // k_80 never used by forward
    }
    {   // t = 0: C==0
        float a1 = fmaf(0.1f, v0, v1);
        float a2 = fmaf(0.1f, a1, v2);
        kk[0] = T.dm[0] * a2;
    }

    // ---- forward rollout: pure-register; p_t lands in OUTPUT layout ----
#pragma unroll
    for (int t = 0; t < 80; ++t) {
        float u  = fmaf(T.k0[t], p, fmaf(T.k1[t], ve, fmaf(T.k2[t], ac, kk[t])));
        float pn = fmaf(0.001f, u, fmaf(0.01f, ac, fmaf(0.1f, ve, p)));
        float vn = fmaf(0.01f,  u, fmaf(0.1f,  ac, ve));
        ac = fmaf(0.1f, u, ac);
        p = pn; ve = vn;
        row[t * 3] = p;                        // slot t*3+axis == out[t][axis]
    }
}

// ---------------------------------------------------------------------------
// BPB = 16 batches/block, NTH = 96, grid = 512 -> 2 blocks/CU (LDS 15.6 KB).
// wave0: lanes 0..31 = axes 0,1 x 16 batches (type 0, uniform);
// wave1: lanes 0..15 = yaw x 16 batches (type 1, uniform).
// ONE barrier (recursion -> writeback); no staging phase.
// LDS stride 244: forward-pass write banks (bb*20 + 3t + axis)%32 -> 2-way
// (free); writeback is contiguous float4 bursts.
// ---------------------------------------------------------------------------
#define BPB 16
#define RS  244
#define NTH 96

__global__ __launch_bounds__(NTH) void lqr_fused_kernel(
        const float* __restrict__ ego,   // (8192, 9)
        const float* __restrict__ ap,    // (8192, 6, 80, 3)
        float* __restrict__ out) {       // (8192, 80, 3)
    __shared__ float sm[BPB * RS];       // 15616 B
    const int tid = threadIdx.x;
    const int b0  = blockIdx.x * BPB;

    // ---- role assignment (wave-uniform type) ----
    const int w    = tid >> 6;           // 0: axes 0,1 | 1: yaw
    const int lane = tid & 63;
    const bool act = (w == 0) ? (lane < 32) : (lane < 16);
    const int bb   = (w == 0) ? (lane & 15) : lane;
    const int axis = (w == 0) ? (lane >> 4) : 2;
    const int b    = b0 + bb;

    // ego loads issued first, consumed only at forward start (long slack)
    float xp = 0.f, xv = 0.f, xa = 0.f;
    if (act) {
        xp = ego[b * 9 + axis];
        xv = ego[b * 9 + 3 + axis];
        xa = ego[b * 9 + 6 + axis];
    }

    const float* gt = ap + (size_t)b * 1440 + 1200 + axis;
    float* row = sm + bb * RS + axis;
    if (w == 0) { if (act) do_axis<0>(gt, row, xp, xv, xa); }
    else        { if (act) do_axis<1>(gt, row, xp, xv, xa); }
    __syncthreads();

    // ---- writeback: contiguous copy (LDS already in out layout) ----
#pragma unroll
    for (int j = 0; j < 10; ++j) {
        const int i   = tid + NTH * j;
        const int bb2 = i / 60, c = i - bb2 * 60;
        *(float4*)(out + (size_t)(b0 + bb2) * 240 + 4 * c) =
            *(const float4*)&sm[bb2 * RS + 4 * c];
    }
}

extern "C" void kernel_launch(void* const* d_in, const int* in_sizes, int n_in,
                              void* d_out, int out_size, void* d_ws, size_t ws_size,
                              hipStream_t stream) {
    const float* ego = (const float*)d_in[0];   // (8192, 9)
    const float* ap  = (const float*)d_in[1];   // (8192, 6, 80, 3)
    float*       out = (float*)d_out;           // (8192, 80, 3)
    lqr_fused_kernel<<<8192 / BPB, NTH, 0, stream>>>(ego, ap, out);
}

// Round 12
// 11.649 us; speedup vs baseline: 1.1030x; 1.1030x over previous
//
#include <hip/hip_runtime.h>

// ---------------------------------------------------------------------------
// 9-state/3-control LQR decouples per axis into a 3-state (p,v,a | jerk)
// chain; axes 0,1 = type 0, axis 2 (yaw) = type 1. Riccati table computed at
// COMPILE TIME (double precision) and folded to literals via full unroll +
// template-constant type. Recursion dependent chain is REGISTER-ONLY (kk[80]
// constant-indexed -> VGPRs); LDS only for coalesced staging/writeback.
// This round (vs R8, single variable): NTH 96 -> 256. Staging/writeback get
// 4 waves/block (8 waves/CU at 2 blocks/CU) to hide HBM latency in the
// memory phases; recursion lanes unchanged (waves 2-3 barrier-wait, free).
// ---------------------------------------------------------------------------
struct Tbl {
    float qx0[81], qx1[81], qx2[81], dm[81];   // Qxu, dm = DT * (-1/Quu)
    float k0[81],  k1[81],  k2[81];            // feedback gains K_t
};

constexpr Tbl make_tbl(int TY) {
    Tbl T{};
    const double dt = 0.1, dt2 = 0.01, dt3 = 0.001;
    const double cxp = TY ? 10.0 : 1.0;        // YAW_W vs 1
    const double cxv = TY ? 1.0  : 0.0;        // YAW_VEL_W vs 0
    double v00=0, v01=0, v02=0, v11=0, v12=0, v22=0;
    for (int t = 80; t >= 0; --t) {
        const double on = (t >= 1) ? 1.0 : 0.0;     // C[0] == 0
        double Vb0 = v00*dt3 + v01*dt2 + v02*dt;
        double Vb1 = v01*dt3 + v11*dt2 + v12*dt;
        double Vb2 = v02*dt3 + v12*dt2 + v22*dt;
        double Quu = on*0.1 + dt3*Vb0 + dt2*Vb1 + dt*Vb2;
        double Qxu0 = Vb0;
        double Qxu1 = dt*Vb0 + Vb1;
        double Qxu2 = dt2*Vb0 + dt*Vb1 + Vb2;
        double M01 = dt*v00 + v01;
        double M02 = dt2*v00 + dt*v01 + v02;
        double M11 = dt*v01 + v11;
        double M12 = dt2*v01 + dt*v11 + v12;
        double M22 = dt2*v02 + dt*v12 + v22;
        double Q00 = on*cxp + v00;
        double Q11 = on*cxv + dt*M01 + M11;
        double Q12 = dt*M02 + M12;
        double Q22 = on*1.0 + dt2*M02 + dt*M12 + M22;
        double m = -1.0 / Quu;
        T.qx0[t] = (float)Qxu0; T.qx1[t] = (float)Qxu1; T.qx2[t] = (float)Qxu2;
        T.dm[t]  = (float)(dt * m);
        T.k0[t]  = (float)(Qxu0*m); T.k1[t] = (float)(Qxu1*m); T.k2[t] = (float)(Qxu2*m);
        v00 = Q00 + m*Qxu0*Qxu0;               // Vn = Qxx + m*Qxu*Qxu^T
        v01 = M01 + m*Qxu0*Qxu1;               // (Qux + Quu*K == 0)
        v02 = M02 + m*Qxu0*Qxu2;
        v11 = Q11 + m*Qxu1*Qxu1;
        v12 = Q12 + m*Qxu1*Qxu2;
        v22 = Q22 + m*Qxu2*Qxu2;
    }
    return T;
}

// Register-resident recursion. `row` = &sm[bb*RS + axis]; all offsets
// compile-time constants after unroll; kk[] indices constant -> VGPRs.
template <int TY>
__device__ __forceinline__ void do_axis(float* __restrict__ row,
                                        float p, float ve, float ac) {
    constexpr Tbl T = make_tbl(TY);
    constexpr float wp = TY ? 10.f : 1.f;
    float kk[80];

    // ---- backward: v-recursion in registers; tg reads are off-chain ----
    float v0 = 0.f, v1 = 0.f, v2 = 0.f;
#pragma unroll
    for (int t = 80; t >= 1; --t) {
        float tg = row[(t - 1) * 3];           // independent address, batchable
        float a1 = fmaf(0.1f, v0, v1);
        float a2 = fmaf(0.1f, a1, v2);
        float k  = T.dm[t] * a2;               // k_t = -(b^T v)/Quu
        v0 = fmaf(T.qx0[t], k, v0) - wp * tg;
        v1 = fmaf(T.qx1[t], k, a1);
        v2 = fmaf(T.qx2[t], k, a2);
        if (t <= 79) kk[t] = k;                // k_80 never used by forward
    }
    {   // t = 0: C==0
        float a1 = fmaf(0.1f, v0, v1);
        float a2 = fmaf(0.1f, a1, v2);
        kk[0] = T.dm[0] * a2;
    }

    // ---- forward rollout: pure-register; p_t lands in OUTPUT layout ----
#pragma unroll
    for (int t = 0; t < 80; ++t) {
        float u  = fmaf(T.k0[t], p, fmaf(T.k1[t], ve, fmaf(T.k2[t], ac, kk[t])));
        float pn = fmaf(0.001f, u, fmaf(0.01f, ac, fmaf(0.1f, ve, p)));
        float vn = fmaf(0.01f,  u, fmaf(0.1f,  ac, ve));
        ac = fmaf(0.1f, u, ac);
        p = pn; ve = vn;
        row[t * 3] = p;                        // slot t*3+axis == out[t][axis]
    }
}

// ---------------------------------------------------------------------------
// BPB = 16 batches/block, NTH = 256 (4 waves), grid = 512 -> 2 blocks/CU,
// 8 waves/CU. Staging/writeback: 960 float4 over 256 threads (3.75 iters).
// Recursion: wave0 lanes 0..31 = axes 0,1 x 16 batches (type 0, uniform);
// wave1 lanes 0..15 = yaw (type 1, uniform); waves 2,3 barrier-wait.
// LDS stride 244: recursion banks (bb*20 + 3t + axis)%32 -> 16 banks x
// 2-way (free); staging/writeback are contiguous float4 bursts.
// ---------------------------------------------------------------------------
#define BPB 16
#define RS  244
#define NTH 256

__global__ __launch_bounds__(NTH) void lqr_fused_kernel(
        const float* __restrict__ ego,   // (8192, 9)
        const float* __restrict__ ap,    // (8192, 6, 80, 3)
        float* __restrict__ out) {       // (8192, 80, 3)
    __shared__ float sm[BPB * RS];       // 15616 B
    const int tid = threadIdx.x;
    const int b0  = blockIdx.x * BPB;

    // ---- stage targets: 16 batches x 60 float4 = 960, coalesced ----
#pragma unroll
    for (int j = 0; j < 4; ++j) {
        const int i = tid + NTH * j;
        if (i < BPB * 60) {
            const int bb = i / 60, c = i - bb * 60;
            *(float4*)&sm[bb * RS + 4 * c] =
                *(const float4*)(ap + (size_t)(b0 + bb) * 1440 + 1200 + 4 * c);
        }
    }

    // ---- role assignment (wave-uniform type) ----
    const int w    = tid >> 6;           // 0: axes 0,1 | 1: yaw | 2,3: idle
    const int lane = tid & 63;
    const bool act = (w == 0) ? (lane < 32) : (w == 1 ? (lane < 16) : false);
    const int bb   = (w == 0) ? (lane & 15) : lane;
    const int axis = (w == 0) ? (lane >> 4) : 2;
    const int b    = b0 + (bb & 15);

    // ego loads issued pre-barrier, consumed only at forward start
    float xp = 0.f, xv = 0.f, xa = 0.f;
    if (act) {
        xp = ego[b * 9 + axis];
        xv = ego[b * 9 + 3 + axis];
        xa = ego[b * 9 + 6 + axis];
    }
    __syncthreads();

    if (w == 0)      { if (act) do_axis<0>(sm + (bb & 15) * RS + axis, xp, xv, xa); }
    else if (w == 1) { if (act) do_axis<1>(sm + (bb & 15) * RS + 2,    xp, xv, xa); }
    __syncthreads();

    // ---- writeback: contiguous copy (LDS already in out layout) ----
#pragma unroll
    for (int j = 0; j < 4; ++j) {
        const int i = tid + NTH * j;
        if (i < BPB * 60) {
            const int bb2 = i / 60, c = i - bb2 * 60;
            *(float4*)(out + (size_t)(b0 + bb2) * 240 + 4 * c) =
                *(const float4*)&sm[bb2 * RS + 4 * c];
        }
    }
}

extern "C" void kernel_launch(void* const* d_in, const int* in_sizes, int n_in,
                              void* d_out, int out_size, void* d_ws, size_t ws_size,
                              hipStream_t stream) {
    const float* ego = (const float*)d_in[0];   // (8192, 9)
    const float* ap  = (const float*)d_in[1];   // (8192, 6, 80, 3)
    float*       out = (float*)d_out;           // (8192, 80, 3)
    lqr_fused_kernel<<<8192 / BPB, NTH, 0, stream>>>(ego, ap, out);
}